// Round 7
// baseline (10757.084 us; speedup 1.0000x reference)
//
#include <hip/hip_runtime.h>
#include <stdint.h>

#define T_STEPS 512
#define H_DIM   256
#define NBG     16
#define NCG     8
#define BM      16
#define NTHR    512

typedef unsigned short u16;
typedef __attribute__((ext_vector_type(8))) short short8;
typedef __attribute__((ext_vector_type(4))) float f32x4;

__device__ __forceinline__ u16 f2bf(float f) {
    unsigned u = __float_as_uint(f);
    unsigned r = (u + 0x7fffu + ((u >> 16) & 1u)) >> 16;
    return (u16)r;
}
__device__ __forceinline__ float bf2f(u16 h) {
    return __uint_as_float(((unsigned)h) << 16);
}
__device__ __forceinline__ float sigmoid_f(float v) {
    return 1.0f / (1.0f + __expf(-v));
}
__device__ __forceinline__ float tanh_f(float v) {
    float e = __expf(2.0f * v);
    return 1.0f - 2.0f / (e + 1.0f);
}

// Grid: 128 blocks = 16 batch-groups (bg = blockIdx&15) x 8 col-groups (g).
// (Note: all 8 col-groups of a bg share blockIdx%8 == bg%8 — same XCD under
//  round-robin placement; perf-only, correctness is agent-scope.)
// W_hh slice persistent in registers (bf16 hi/lo 3-product split).
// Per step: all-lane acquire-spin -> A-frags global->reg -> MFMA ->
// per-wave gtmp transpose (no barrier) -> pointwise -> direct h store ->
// ONE __syncthreads -> tid0 release. y-projection off critical path (wave0,g0).
__global__ void __launch_bounds__(NTHR, 1)
lstm_pipe_kernel(const float* __restrict__ x,
                 const float* __restrict__ W_ih,
                 const float* __restrict__ W_hh,
                 const float* __restrict__ b_ih,
                 const float* __restrict__ b_hh,
                 const float* __restrict__ W_lin,
                 const float* __restrict__ b_lin,
                 float* __restrict__ out,
                 u16* __restrict__ hb_hi,
                 u16* __restrict__ hb_lo,
                 unsigned* __restrict__ cnt)
{
    const int tid  = threadIdx.x;
    const int bg   = blockIdx.x & (NBG - 1);
    const int g    = blockIdx.x >> 4;
    const int wave = tid >> 6;
    const int lane = tid & 63;
    const int cl   = lane & 15;
    const int kgrp = lane >> 4;

    __shared__ float gtmp[8 * 16 * 17];   // per-wave-private transpose buffer
    __shared__ float wlin[H_DIM];

    // ---- W_hh fragments (persistent in registers), bf16 hi/lo split ----
    // B-frag (16x16x32): lane holds B[k = kt*32 + kgrp*8 + e][col = cl]
    short8 wfh[8], wfl[8];
    {
        const int c    = wave * 16 + cl;                       // 0..127
        const int wrow = (c & 3) * H_DIM + g * 32 + (c >> 2);  // gate*H + hidden
        const float* wr = W_hh + (size_t)wrow * H_DIM;
        #pragma unroll
        for (int kt = 0; kt < 8; ++kt) {
            const int k0 = kt * 32 + kgrp * 8;
            short8 hi8, lo8;
            #pragma unroll
            for (int e = 0; e < 8; ++e) {
                float w = wr[k0 + e];
                u16 hi = f2bf(w);
                u16 lo = f2bf(w - bf2f(hi));
                hi8[e] = (short)hi;
                lo8[e] = (short)lo;
            }
            wfh[kt] = hi8;
            wfl[kt] = lo8;
        }
    }

    // ---- pointwise lane mapping: (m_p, jloc_p) ----
    const int m_p     = lane & 15;
    const int jq      = lane >> 4;
    const int jloc_p  = wave * 4 + jq;        // 0..31
    const int jglob_p = g * 32 + jloc_p;
    float bias4[4], wihr[4][3];
    #pragma unroll
    for (int gi = 0; gi < 4; ++gi) {
        const int row = gi * H_DIM + jglob_p;
        bias4[gi]  = b_ih[row] + b_hh[row];
        wihr[gi][0] = W_ih[row * 3 + 0];
        wihr[gi][1] = W_ih[row * 3 + 1];
        wihr[gi][2] = W_ih[row * 3 + 2];
    }
    if (tid < H_DIM) wlin[tid] = W_lin[tid];
    const float blin = b_lin[0];
    const float* xrow = x + (size_t)(bg * BM + m_p) * (T_STEPS * 3);

    const int laneoff = cl * H_DIM + kgrp * 8;   // A-frag per-lane offset
    float cstate = 0.0f;

    for (int t = 0; t < T_STEPS; ++t) {
        // x_t for this lane's batch row (independent of h; issues early)
        const float x0 = xrow[t * 3 + 0];
        const float x1 = xrow[t * 3 + 1];
        const float x2 = xrow[t * 3 + 2];

        f32x4 acc0 = {0.f, 0.f, 0.f, 0.f};
        f32x4 acc1 = {0.f, 0.f, 0.f, 0.f};
        short8 ah[8], al[8];
        if (t > 0) {
            const unsigned fidx = (unsigned)(t - 1) * NBG + (unsigned)bg;
            // all lanes spin (single request per wave: uniform address)
            while (__hip_atomic_load(&cnt[fidx], __ATOMIC_ACQUIRE,
                                     __HIP_MEMORY_SCOPE_AGENT) < NCG)
                __builtin_amdgcn_s_sleep(1);
            const int slot = (t - 1) & 1;
            const u16* bh = hb_hi + (size_t)(slot * NBG + bg) * (BM * H_DIM) + laneoff;
            const u16* bl = hb_lo + (size_t)(slot * NBG + bg) * (BM * H_DIM) + laneoff;
            #pragma unroll
            for (int kt = 0; kt < 8; ++kt) {
                ah[kt] = *(const short8*)&bh[kt * 32];
                al[kt] = *(const short8*)&bl[kt * 32];
            }
            // gates[16, tile16] += h_{t-1} @ Wslice^T   (3-product bf16 split)
            #pragma unroll
            for (int kt = 0; kt < 8; ++kt) {
                acc0 = __builtin_amdgcn_mfma_f32_16x16x32_bf16(ah[kt], wfh[kt], acc0, 0, 0, 0);
                acc1 = __builtin_amdgcn_mfma_f32_16x16x32_bf16(ah[kt], wfl[kt], acc1, 0, 0, 0);
                acc0 = __builtin_amdgcn_mfma_f32_16x16x32_bf16(al[kt], wfh[kt], acc0, 0, 0, 0);
            }
        }
        // D layout: col(c)=cl, row(m)=kgrp*4+r. Transpose through per-wave gtmp
        // rows [wave*16, wave*16+16) — written AND read only by this wave:
        // no __syncthreads needed, lgkmcnt ordering suffices.
        #pragma unroll
        for (int r = 0; r < 4; ++r)
            gtmp[(wave * 16 + cl) * 17 + kgrp * 4 + r] = acc0[r] + acc1[r];
        float gv[4];
        #pragma unroll
        for (int gi = 0; gi < 4; ++gi) {
            float pre = gtmp[(wave * 16 + jq * 4 + gi) * 17 + m_p];
            pre += bias4[gi] + wihr[gi][0] * x0 + wihr[gi][1] * x1 + wihr[gi][2] * x2;
            gv[gi] = pre;
        }
        const float ig = sigmoid_f(gv[0]);
        const float fg = sigmoid_f(gv[1]);
        const float gg = tanh_f(gv[2]);
        const float og = sigmoid_f(gv[3]);
        cstate = fg * cstate + ig * gg;
        const float hval = og * tanh_f(cstate);
        {   // publish own h element directly (bf16 hi/lo pair)
            const int slot_t = t & 1;
            const size_t goff = (size_t)(slot_t * NBG + bg) * (BM * H_DIM)
                              + (size_t)m_p * H_DIM + jglob_p;
            const u16 hhi = f2bf(hval);
            hb_hi[goff] = hhi;
            hb_lo[goff] = f2bf(hval - bf2f(hhi));
        }
        __syncthreads();   // drains all waves' h stores (vmcnt 0) before release
        if (tid == 0)
            __hip_atomic_fetch_add(&cnt[(unsigned)t * NBG + (unsigned)bg], 1u,
                                   __ATOMIC_RELEASE, __HIP_MEMORY_SCOPE_AGENT);
        // y_{t-1} = relu(W_lin . h_{t-1} + b): wave0 of g0 has full h_{t-1}
        // in its A-frags. Off the critical path (after release).
        if (g == 0 && wave == 0 && t > 0) {
            float part = 0.f;
            #pragma unroll
            for (int kt = 0; kt < 8; ++kt) {
                const f32x4 w0 = *(const f32x4*)&wlin[kt * 32 + kgrp * 8];
                const f32x4 w1 = *(const f32x4*)&wlin[kt * 32 + kgrp * 8 + 4];
                #pragma unroll
                for (int e = 0; e < 4; ++e) {
                    part += (bf2f((u16)ah[kt][e])     + bf2f((u16)al[kt][e]))     * w0[e];
                    part += (bf2f((u16)ah[kt][4 + e]) + bf2f((u16)al[kt][4 + e])) * w1[e];
                }
            }
            part += __shfl_xor(part, 16);
            part += __shfl_xor(part, 32);
            if (lane < BM)
                out[(size_t)(bg * BM + lane) * T_STEPS + (t - 1)] =
                    fmaxf(part + blin, 0.f);
        }
    }
    // final column y[:, T-1]
    if (g == 0 && wave == 0) {
        const unsigned fidx = (unsigned)(T_STEPS - 1) * NBG + (unsigned)bg;
        while (__hip_atomic_load(&cnt[fidx], __ATOMIC_ACQUIRE,
                                 __HIP_MEMORY_SCOPE_AGENT) < NCG)
            __builtin_amdgcn_s_sleep(1);
        const int slot = (T_STEPS - 1) & 1;
        const u16* bh = hb_hi + (size_t)(slot * NBG + bg) * (BM * H_DIM) + laneoff;
        const u16* bl = hb_lo + (size_t)(slot * NBG + bg) * (BM * H_DIM) + laneoff;
        float part = 0.f;
        #pragma unroll
        for (int kt = 0; kt < 8; ++kt) {
            const short8 ahf = *(const short8*)&bh[kt * 32];
            const short8 alf = *(const short8*)&bl[kt * 32];
            const f32x4 w0 = *(const f32x4*)&wlin[kt * 32 + kgrp * 8];
            const f32x4 w1 = *(const f32x4*)&wlin[kt * 32 + kgrp * 8 + 4];
            #pragma unroll
            for (int e = 0; e < 4; ++e) {
                part += (bf2f((u16)ahf[e])     + bf2f((u16)alf[e]))     * w0[e];
                part += (bf2f((u16)ahf[4 + e]) + bf2f((u16)alf[4 + e])) * w1[e];
            }
        }
        part += __shfl_xor(part, 16);
        part += __shfl_xor(part, 32);
        if (lane < BM)
            out[(size_t)(bg * BM + lane) * T_STEPS + (T_STEPS - 1)] =
                fmaxf(part + blin, 0.f);
    }
}

extern "C" void kernel_launch(void* const* d_in, const int* in_sizes, int n_in,
                              void* d_out, int out_size, void* d_ws, size_t ws_size,
                              hipStream_t stream) {
    (void)in_sizes; (void)n_in; (void)out_size; (void)ws_size;
    const float* x     = (const float*)d_in[0];
    const float* W_ih  = (const float*)d_in[1];
    const float* W_hh  = (const float*)d_in[2];
    const float* b_ih  = (const float*)d_in[3];
    const float* b_hh  = (const float*)d_in[4];
    const float* W_lin = (const float*)d_in[5];
    const float* b_lin = (const float*)d_in[6];
    float* out = (float*)d_out;

    char* ws = (char*)d_ws;
    unsigned* cnt = (unsigned*)ws;                        // 512*16*4   = 32768 B
    u16* hb_hi = (u16*)(ws + 32768);                      // 2*16*16*256*2 = 262144 B
    u16* hb_lo = (u16*)(ws + 32768 + 262144);             // 262144 B

    hipMemsetAsync(cnt, 0, T_STEPS * NBG * sizeof(unsigned), stream);
    lstm_pipe_kernel<<<dim3(NBG * NCG), dim3(NTHR), 0, stream>>>(
        x, W_ih, W_hh, b_ih, b_hh, W_lin, b_lin, out, hb_hi, hb_lo, cnt);
}

// Round 8
// 3700.364 us; speedup vs baseline: 2.9070x; 2.9070x over previous
//
#include <hip/hip_runtime.h>
#include <stdint.h>

#define T_STEPS 512
#define H_DIM   256
#define NBG     16
#define NCG     8
#define BM      16
#define NTHR    512

typedef unsigned short u16;
typedef __attribute__((ext_vector_type(8))) short short8;
typedef __attribute__((ext_vector_type(4))) float f32x4;

__device__ __forceinline__ u16 f2bf(float f) {
    unsigned u = __float_as_uint(f);
    unsigned r = (u + 0x7fffu + ((u >> 16) & 1u)) >> 16;
    return (u16)r;
}
__device__ __forceinline__ float bf2f(u16 h) {
    return __uint_as_float(((unsigned)h) << 16);
}
__device__ __forceinline__ float sigmoid_f(float v) {
    return 1.0f / (1.0f + __expf(-v));
}
__device__ __forceinline__ float tanh_f(float v) {
    float e = __expf(2.0f * v);
    return 1.0f - 2.0f / (e + 1.0f);
}

// Grid: 128 blocks = 16 batch-groups (bg) x 8 col-groups (g). W_hh slice in
// registers (bf16 hi/lo 3-product). Flags: one word per (t,bg,g) -> producers
// do ONE release STORE each (no RMW serialization); consumer wave0 lanes 0-7
// acquire-poll the 8 words (round-1-proven single-wave poll + barrier fanout).
// Per step: [wave0 poll] A-barrier -> A-frags global->reg -> MFMA -> gtmp2
// transposed write -> B-barrier -> pointwise (b128 gtmp2 read, coalesced h
// store) -> C-barrier (vmcnt drain) -> tid0 release store. y-proj off
// critical path on g0/wave0 registers.
__global__ void __launch_bounds__(NTHR, 1)
lstm_pipe_kernel(const float* __restrict__ x,
                 const float* __restrict__ W_ih,
                 const float* __restrict__ W_hh,
                 const float* __restrict__ b_ih,
                 const float* __restrict__ b_hh,
                 const float* __restrict__ W_lin,
                 const float* __restrict__ b_lin,
                 float* __restrict__ out,
                 u16* __restrict__ hb_hi,
                 u16* __restrict__ hb_lo,
                 unsigned* __restrict__ flg)
{
    const int tid  = threadIdx.x;
    const int bg   = blockIdx.x & (NBG - 1);
    const int g    = blockIdx.x >> 4;
    const int wave = tid >> 6;
    const int lane = tid & 63;
    const int cl   = lane & 15;   // MFMA A-row / D-col
    const int kgrp = lane >> 4;

    __shared__ float gtmp2[BM * 132];   // [m][c_block] pre-activations, pad 132
    __shared__ float wlin[H_DIM];

    // ---- W_hh fragments (persistent in registers), bf16 hi/lo split ----
    // B-frag (16x16x32): lane holds B[k = kt*32 + kgrp*8 + e][col = cl]
    short8 wfh[8], wfl[8];
    {
        const int c    = wave * 16 + cl;                       // 0..127
        const int wrow = (c & 3) * H_DIM + g * 32 + (c >> 2);  // gate*H + hidden
        const float* wr = W_hh + (size_t)wrow * H_DIM;
        #pragma unroll
        for (int kt = 0; kt < 8; ++kt) {
            const int k0 = kt * 32 + kgrp * 8;
            short8 hi8, lo8;
            #pragma unroll
            for (int e = 0; e < 8; ++e) {
                float w = wr[k0 + e];
                u16 hi = f2bf(w);
                u16 lo = f2bf(w - bf2f(hi));
                hi8[e] = (short)hi;
                lo8[e] = (short)lo;
            }
            wfh[kt] = hi8;
            wfl[kt] = lo8;
        }
    }

    // ---- pointwise mapping: tid -> (m2 = tid>>5, j2 = tid&31), coalesced ----
    const int m2     = tid >> 5;
    const int j2     = tid & 31;
    const int jglob2 = g * 32 + j2;
    float bias4[4], wihr[4][3];
    #pragma unroll
    for (int gi = 0; gi < 4; ++gi) {
        const int row = gi * H_DIM + jglob2;
        bias4[gi]  = b_ih[row] + b_hh[row];
        wihr[gi][0] = W_ih[row * 3 + 0];
        wihr[gi][1] = W_ih[row * 3 + 1];
        wihr[gi][2] = W_ih[row * 3 + 2];
    }
    if (tid < H_DIM) wlin[tid] = W_lin[tid];
    const float blin = b_lin[0];
    const float* xrow = x + (size_t)(bg * BM + m2) * (T_STEPS * 3);

    const int laneoff = cl * H_DIM + kgrp * 8;   // A-frag per-lane elem offset
    float cstate = 0.0f;

    for (int t = 0; t < T_STEPS; ++t) {
        // x_t (independent of h) — issue before the wait
        const float x0 = xrow[t * 3 + 0];
        const float x1 = xrow[t * 3 + 1];
        const float x2 = xrow[t * 3 + 2];

        f32x4 acc0 = {0.f, 0.f, 0.f, 0.f};
        f32x4 acc1 = {0.f, 0.f, 0.f, 0.f};
        short8 ah[8], al[8];
        if (t > 0) {
            // wave0 polls the 8 per-producer flag words (lanes 0-7)
            if (wave == 0) {
                const unsigned fbase = ((unsigned)(t - 1) * NBG + (unsigned)bg) * 16u;
                bool ok;
                do {
                    unsigned v = 1u;
                    if (lane < NCG)
                        v = __hip_atomic_load(&flg[fbase + lane], __ATOMIC_ACQUIRE,
                                              __HIP_MEMORY_SCOPE_AGENT);
                    ok = __all(v != 0u);
                    if (!ok) __builtin_amdgcn_s_sleep(1);
                } while (!ok);
            }
            __syncthreads();   // A: fan out "h_{t-1} visible"
            const int slot = (t - 1) & 1;
            const u16* bh = hb_hi + (size_t)(slot * NBG + bg) * (BM * H_DIM) + laneoff;
            const u16* bl = hb_lo + (size_t)(slot * NBG + bg) * (BM * H_DIM) + laneoff;
            #pragma unroll
            for (int kt = 0; kt < 8; ++kt) {
                ah[kt] = *(const short8*)&bh[kt * 32];
                al[kt] = *(const short8*)&bl[kt * 32];
            }
            // gates[16,16-tile] += h_{t-1} @ Wslice^T  (3-product bf16 split)
            #pragma unroll
            for (int kt = 0; kt < 8; ++kt) {
                acc0 = __builtin_amdgcn_mfma_f32_16x16x32_bf16(ah[kt], wfh[kt], acc0, 0, 0, 0);
                acc1 = __builtin_amdgcn_mfma_f32_16x16x32_bf16(ah[kt], wfl[kt], acc1, 0, 0, 0);
                acc0 = __builtin_amdgcn_mfma_f32_16x16x32_bf16(al[kt], wfh[kt], acc0, 0, 0, 0);
            }
        } else {
            __syncthreads();   // A (uniform structure; also covers wlin init)
        }
        // D layout: col=cl, row m=kgrp*4+r. Store transposed: gtmp2[m][c_block]
        // (c_block = wave*16+cl). Bank pattern 2-way max (free).
        #pragma unroll
        for (int r = 0; r < 4; ++r)
            gtmp2[(kgrp * 4 + r) * 132 + wave * 16 + cl] = acc0[r] + acc1[r];
        __syncthreads();       // B: transpose visible cross-wave
        {
            // one conflict-free b128 read: 4 gates for (m2, j2)
            const f32x4 gq = *(const f32x4*)&gtmp2[m2 * 132 + j2 * 4];
            float gv[4];
            #pragma unroll
            for (int gi = 0; gi < 4; ++gi)
                gv[gi] = gq[gi] + bias4[gi]
                       + wihr[gi][0] * x0 + wihr[gi][1] * x1 + wihr[gi][2] * x2;
            const float ig = sigmoid_f(gv[0]);
            const float fg = sigmoid_f(gv[1]);
            const float gg = tanh_f(gv[2]);
            const float og = sigmoid_f(gv[3]);
            cstate = fg * cstate + ig * gg;
            const float hval = og * tanh_f(cstate);
            // coalesced publish: 32 consecutive u16 per row per wave-half
            const int slot_t = t & 1;
            const size_t goff = (size_t)(slot_t * NBG + bg) * (BM * H_DIM)
                              + (size_t)m2 * H_DIM + jglob2;
            const u16 hhi = f2bf(hval);
            hb_hi[goff] = hhi;
            hb_lo[goff] = f2bf(hval - bf2f(hhi));
        }
        __syncthreads();       // C: drains all waves' h stores (vmcnt 0)
        if (tid == 0)
            __hip_atomic_store(&flg[((unsigned)t * NBG + (unsigned)bg) * 16u + (unsigned)g],
                               1u, __ATOMIC_RELEASE, __HIP_MEMORY_SCOPE_AGENT);
        // y_{t-1} = relu(W_lin . h_{t-1} + b): g0/wave0 owns full h_{t-1} rows
        // 0..15 in its A-frags. Off the critical path (after release).
        if (g == 0 && wave == 0 && t > 0) {
            float part = 0.f;
            #pragma unroll
            for (int kt = 0; kt < 8; ++kt) {
                const f32x4 w0 = *(const f32x4*)&wlin[kt * 32 + kgrp * 8];
                const f32x4 w1 = *(const f32x4*)&wlin[kt * 32 + kgrp * 8 + 4];
                #pragma unroll
                for (int e = 0; e < 4; ++e) {
                    part += (bf2f((u16)ah[kt][e])     + bf2f((u16)al[kt][e]))     * w0[e];
                    part += (bf2f((u16)ah[kt][4 + e]) + bf2f((u16)al[kt][4 + e])) * w1[e];
                }
            }
            part += __shfl_xor(part, 16);
            part += __shfl_xor(part, 32);
            if (lane < BM)
                out[(size_t)(bg * BM + lane) * T_STEPS + (t - 1)] =
                    fmaxf(part + blin, 0.f);
        }
    }
    // final column y[:, T-1]
    if (g == 0 && wave == 0) {
        const unsigned fbase = ((unsigned)(T_STEPS - 1) * NBG + (unsigned)bg) * 16u;
        bool ok;
        do {
            unsigned v = 1u;
            if (lane < NCG)
                v = __hip_atomic_load(&flg[fbase + lane], __ATOMIC_ACQUIRE,
                                      __HIP_MEMORY_SCOPE_AGENT);
            ok = __all(v != 0u);
            if (!ok) __builtin_amdgcn_s_sleep(1);
        } while (!ok);
        const int slot = (T_STEPS - 1) & 1;
        const u16* bh = hb_hi + (size_t)(slot * NBG + bg) * (BM * H_DIM) + laneoff;
        const u16* bl = hb_lo + (size_t)(slot * NBG + bg) * (BM * H_DIM) + laneoff;
        float part = 0.f;
        #pragma unroll
        for (int kt = 0; kt < 8; ++kt) {
            const short8 ahf = *(const short8*)&bh[kt * 32];
            const short8 alf = *(const short8*)&bl[kt * 32];
            const f32x4 w0 = *(const f32x4*)&wlin[kt * 32 + kgrp * 8];
            const f32x4 w1 = *(const f32x4*)&wlin[kt * 32 + kgrp * 8 + 4];
            #pragma unroll
            for (int e = 0; e < 4; ++e) {
                part += (bf2f((u16)ahf[e])     + bf2f((u16)alf[e]))     * w0[e];
                part += (bf2f((u16)ahf[4 + e]) + bf2f((u16)alf[4 + e])) * w1[e];
            }
        }
        part += __shfl_xor(part, 16);
        part += __shfl_xor(part, 32);
        if (lane < BM)
            out[(size_t)(bg * BM + lane) * T_STEPS + (T_STEPS - 1)] =
                fmaxf(part + blin, 0.f);
    }
}

extern "C" void kernel_launch(void* const* d_in, const int* in_sizes, int n_in,
                              void* d_out, int out_size, void* d_ws, size_t ws_size,
                              hipStream_t stream) {
    (void)in_sizes; (void)n_in; (void)out_size; (void)ws_size;
    const float* x     = (const float*)d_in[0];
    const float* W_ih  = (const float*)d_in[1];
    const float* W_hh  = (const float*)d_in[2];
    const float* b_ih  = (const float*)d_in[3];
    const float* b_hh  = (const float*)d_in[4];
    const float* W_lin = (const float*)d_in[5];
    const float* b_lin = (const float*)d_in[6];
    float* out = (float*)d_out;

    char* ws = (char*)d_ws;
    unsigned* flg = (unsigned*)ws;                 // 512*16*16*4 = 524288 B
    u16* hb_hi = (u16*)(ws + 524288);              // 2*16*16*256*2 = 262144 B
    u16* hb_lo = (u16*)(ws + 524288 + 262144);     // 262144 B

    hipMemsetAsync(flg, 0, (size_t)T_STEPS * NBG * 16 * sizeof(unsigned), stream);
    lstm_pipe_kernel<<<dim3(NBG * NCG), dim3(NTHR), 0, stream>>>(
        x, W_ih, W_hh, b_ih, b_hh, W_lin, b_lin, out, hb_hi, hb_lo, flg);
}

// Round 9
// 1945.065 us; speedup vs baseline: 5.5304x; 1.9024x over previous
//
#include <hip/hip_runtime.h>
#include <stdint.h>

#define T_STEPS 512
#define H_DIM   256
#define NBG     16
#define NCG     8
#define BM      16
#define NTHR    512

typedef unsigned short u16;
typedef unsigned int   u32;
typedef __attribute__((ext_vector_type(8))) short short8;
typedef __attribute__((ext_vector_type(4))) float f32x4;
typedef __attribute__((ext_vector_type(4))) u32   u32x4;

__device__ __forceinline__ u16 f2bf(float f) {
    unsigned u = __float_as_uint(f);
    unsigned r = (u + 0x7fffu + ((u >> 16) & 1u)) >> 16;
    return (u16)r;
}
__device__ __forceinline__ float bf2f(u16 h) {
    return __uint_as_float(((unsigned)h) << 16);
}
__device__ __forceinline__ float sigmoid_f(float v) {
    return 1.0f / (1.0f + __expf(-v));
}
__device__ __forceinline__ float tanh_f(float v) {
    float e = __expf(2.0f * v);
    return 1.0f - 2.0f / (e + 1.0f);
}

// L3-direct (L2-bypass) load: sc0 sc1 reads through to the coherence point.
// No buffer_inv is ever issued -> no L2 flash-invalidate storms.
__device__ __forceinline__ unsigned bypass_load_u32(const unsigned* p) {
    unsigned v;
    asm volatile("global_load_dword %0, %1, off sc0 sc1\n\t"
                 "s_waitcnt vmcnt(0)"
                 : "=v"(v) : "v"(p) : "memory");
    return v;
}
__device__ __forceinline__ void bypass_load_2x16(const u32* p0, const u32* p1,
                                                 u32x4& d0, u32x4& d1) {
    asm volatile("global_load_dwordx4 %0, %2, off sc0 sc1\n\t"
                 "global_load_dwordx4 %1, %3, off sc0 sc1\n\t"
                 "s_waitcnt vmcnt(0)"
                 : "=&v"(d0), "=&v"(d1)
                 : "v"(p0), "v"(p1) : "memory");
}

// Grid: 128 blocks = 16 batch-groups (bg) x 8 col-groups (g). W_hh slice in
// registers (bf16 hi/lo 3-product). h exchanged as ONE packed u32 plane
// ((hi<<16)|lo). Flags: per-producer words; consumer wave0 polls with sc0/sc1
// bypass loads (no acquire -> no L2 invalidates). A-tile staged to LDS once
// per block per step (R1-proven swizzle), MFMA reads LDS. y-proj on wave7,
// overlapped with next step's poll.
__global__ void __launch_bounds__(NTHR, 1)
lstm_pipe_kernel(const float* __restrict__ x,
                 const float* __restrict__ W_ih,
                 const float* __restrict__ W_hh,
                 const float* __restrict__ b_ih,
                 const float* __restrict__ b_hh,
                 const float* __restrict__ W_lin,
                 const float* __restrict__ b_lin,
                 float* __restrict__ out,
                 u32* __restrict__ hb,
                 unsigned* __restrict__ flg)
{
    const int tid  = threadIdx.x;
    const int bg   = blockIdx.x & (NBG - 1);
    const int g    = blockIdx.x >> 4;
    const int wave = tid >> 6;
    const int lane = tid & 63;
    const int cl   = lane & 15;   // MFMA A-row / D-col
    const int kgrp = lane >> 4;

    __shared__ __align__(16) u16 HShi[BM * H_DIM];   // staged h_{t-1} hi (swizzled)
    __shared__ __align__(16) u16 HSlo[BM * H_DIM];   // staged h_{t-1} lo (swizzled)
    __shared__ float gtmp2[BM * 132];                // [m][c_block], conflict-free
    __shared__ float wlin[H_DIM];

    // ---- W_hh fragments (persistent in registers), bf16 hi/lo split ----
    // B-frag (16x16x32): lane holds B[k = kt*32 + kgrp*8 + e][col = cl]
    short8 wfh[8], wfl[8];
    {
        const int c    = wave * 16 + cl;                       // 0..127
        const int wrow = (c & 3) * H_DIM + g * 32 + (c >> 2);  // gate*H + hidden
        const float* wr = W_hh + (size_t)wrow * H_DIM;
        #pragma unroll
        for (int kt = 0; kt < 8; ++kt) {
            const int k0 = kt * 32 + kgrp * 8;
            short8 hi8, lo8;
            #pragma unroll
            for (int e = 0; e < 8; ++e) {
                float w = wr[k0 + e];
                u16 hi = f2bf(w);
                u16 lo = f2bf(w - bf2f(hi));
                hi8[e] = (short)hi;
                lo8[e] = (short)lo;
            }
            wfh[kt] = hi8;
            wfl[kt] = lo8;
        }
    }

    // ---- pointwise mapping (coalesced): m2 = tid>>5, j2 = tid&31 ----
    const int m2     = tid >> 5;
    const int j2     = tid & 31;
    const int jglob2 = g * 32 + j2;
    float bias4[4], wihr[4][3];
    #pragma unroll
    for (int gi = 0; gi < 4; ++gi) {
        const int row = gi * H_DIM + jglob2;
        bias4[gi]  = b_ih[row] + b_hh[row];
        wihr[gi][0] = W_ih[row * 3 + 0];
        wihr[gi][1] = W_ih[row * 3 + 1];
        wihr[gi][2] = W_ih[row * 3 + 2];
    }
    if (tid < H_DIM) wlin[tid] = W_lin[tid];
    const float blin = b_lin[0];
    const float* xrow = x + (size_t)(bg * BM + m2) * (T_STEPS * 3);

    // ---- staging mapping: sm = tid>>5 row, skb = tid&31 col-block ----
    const int sm    = tid >> 5;
    const int skb   = tid & 31;
    const int sdidx = (sm * H_DIM + skb * 8) ^ ((sm & 7) << 3);   // u16 units

    float cstate = 0.0f;

    for (int t = 0; t < T_STEPS; ++t) {
        // x_t (L2-cacheable now; independent of h)
        const float x0 = xrow[t * 3 + 0];
        const float x1 = xrow[t * 3 + 1];
        const float x2 = xrow[t * 3 + 2];

        if (t > 0 && wave == 0) {
            // bypass-poll the 8 producer flags (lanes duplicate mod 8)
            const unsigned fbase = ((unsigned)(t - 1) * NBG + (unsigned)bg) * 16u;
            const unsigned* fp = flg + fbase + (lane & 7);
            for (;;) {
                unsigned v = bypass_load_u32(fp);
                if (__all(v != 0u)) break;
                __builtin_amdgcn_s_sleep(1);
            }
        }
        __syncthreads();   // A: "h_{t-1} visible in L3" fan-out
        if (t > 0) {
            // stage packed h_{t-1} (16KB) L3 -> LDS, unpack to hi/lo planes
            const int slot = (t - 1) & 1;
            const u32* hbase = hb + (size_t)(slot * NBG + bg) * (BM * H_DIM)
                             + sm * H_DIM + skb * 8;
            u32x4 d0, d1;
            bypass_load_2x16(hbase, hbase + 4, d0, d1);
            short8 hi8, lo8;
            #pragma unroll
            for (int e = 0; e < 4; ++e) {
                hi8[e]     = (short)(d0[e] >> 16);
                lo8[e]     = (short)(d0[e] & 0xffffu);
                hi8[4 + e] = (short)(d1[e] >> 16);
                lo8[4 + e] = (short)(d1[e] & 0xffffu);
            }
            *(short8*)&HShi[sdidx] = hi8;
            *(short8*)&HSlo[sdidx] = lo8;
        }
        __syncthreads();   // B: staging visible
        f32x4 acc0 = {0.f, 0.f, 0.f, 0.f};
        f32x4 acc1 = {0.f, 0.f, 0.f, 0.f};
        if (t > 0) {
            // gates[16,16-tile] += h_{t-1} @ Wslice^T  (3-product bf16 split)
            #pragma unroll
            for (int kt = 0; kt < 8; ++kt) {
                const int aidx = (cl * H_DIM + kt * 32 + kgrp * 8) ^ ((cl & 7) << 3);
                const short8 ah = *(const short8*)&HShi[aidx];
                const short8 al = *(const short8*)&HSlo[aidx];
                acc0 = __builtin_amdgcn_mfma_f32_16x16x32_bf16(ah, wfh[kt], acc0, 0, 0, 0);
                acc1 = __builtin_amdgcn_mfma_f32_16x16x32_bf16(ah, wfl[kt], acc1, 0, 0, 0);
                acc0 = __builtin_amdgcn_mfma_f32_16x16x32_bf16(al, wfh[kt], acc0, 0, 0, 0);
            }
        }
        // D layout: col=cl, row m=kgrp*4+r -> transposed store gtmp2[m][c_block]
        #pragma unroll
        for (int r = 0; r < 4; ++r)
            gtmp2[(kgrp * 4 + r) * 132 + wave * 16 + cl] = acc0[r] + acc1[r];
        __syncthreads();   // C: transpose visible cross-wave
        {
            const f32x4 gq = *(const f32x4*)&gtmp2[m2 * 132 + j2 * 4];
            float gv[4];
            #pragma unroll
            for (int gi = 0; gi < 4; ++gi)
                gv[gi] = gq[gi] + bias4[gi]
                       + wihr[gi][0] * x0 + wihr[gi][1] * x1 + wihr[gi][2] * x2;
            const float ig = sigmoid_f(gv[0]);
            const float fg = sigmoid_f(gv[1]);
            const float gg = tanh_f(gv[2]);
            const float og = sigmoid_f(gv[3]);
            cstate = fg * cstate + ig * gg;
            const float hval = og * tanh_f(cstate);
            // packed publish (plain store; release's wbl2 flushes it to L3)
            const u16 hhi = f2bf(hval);
            const u16 hlo = f2bf(hval - bf2f(hhi));
            const int slot_t = t & 1;
            hb[(size_t)(slot_t * NBG + bg) * (BM * H_DIM) + (size_t)m2 * H_DIM + jglob2] =
                ((u32)hhi << 16) | (u32)hlo;
        }
        __syncthreads();   // D: drains all waves' h stores
        if (tid == 0)
            __hip_atomic_store(&flg[((unsigned)t * NBG + (unsigned)bg) * 16u + (unsigned)g],
                               1u, __ATOMIC_RELEASE, __HIP_MEMORY_SCOPE_AGENT);
        // y_{t-1} = relu(W_lin . h_{t-1} + b) on wave7 (g0): HS still holds
        // h_{t-1} until next step's staging (gated by barrier A). Overlaps
        // wave0's poll instead of delaying it.
        if (g == 0 && wave == 7 && t > 0) {
            const int m_y = lane & 15, seg = lane >> 4;
            float part = 0.f;
            #pragma unroll
            for (int kt = 0; kt < 8; ++kt) {
                const int idx = (m_y * H_DIM + kt * 32 + seg * 8) ^ ((m_y & 7) << 3);
                const short8 hh = *(const short8*)&HShi[idx];
                const short8 ll = *(const short8*)&HSlo[idx];
                const float* wl = &wlin[kt * 32 + seg * 8];
                #pragma unroll
                for (int e = 0; e < 8; ++e)
                    part += (bf2f((u16)hh[e]) + bf2f((u16)ll[e])) * wl[e];
            }
            part += __shfl_xor(part, 16);
            part += __shfl_xor(part, 32);
            if (lane < BM)
                out[(size_t)(bg * BM + lane) * T_STEPS + (t - 1)] =
                    fmaxf(part + blin, 0.f);
        }
    }
    // final column y[:, T-1] (g0 wave0; direct packed reads)
    if (g == 0 && wave == 0) {
        const unsigned fbase = ((unsigned)(T_STEPS - 1) * NBG + (unsigned)bg) * 16u;
        const unsigned* fp = flg + fbase + (lane & 7);
        for (;;) {
            unsigned v = bypass_load_u32(fp);
            if (__all(v != 0u)) break;
            __builtin_amdgcn_s_sleep(1);
        }
        const int slot = (T_STEPS - 1) & 1;
        const u32* hbase = hb + (size_t)(slot * NBG + bg) * (BM * H_DIM);
        const int m_y = lane & 15, seg = lane >> 4;
        float part = 0.f;
        #pragma unroll
        for (int kt = 0; kt < 8; ++kt) {
            const u32* p = hbase + m_y * H_DIM + kt * 32 + seg * 8;
            u32x4 d0, d1;
            bypass_load_2x16(p, p + 4, d0, d1);
            const float* wl = &wlin[kt * 32 + seg * 8];
            #pragma unroll
            for (int e = 0; e < 4; ++e) {
                part += (bf2f((u16)(d0[e] >> 16)) + bf2f((u16)(d0[e] & 0xffffu))) * wl[e];
                part += (bf2f((u16)(d1[e] >> 16)) + bf2f((u16)(d1[e] & 0xffffu))) * wl[4 + e];
            }
        }
        part += __shfl_xor(part, 16);
        part += __shfl_xor(part, 32);
        if (lane < BM)
            out[(size_t)(bg * BM + lane) * T_STEPS + (T_STEPS - 1)] =
                fmaxf(part + blin, 0.f);
    }
}

extern "C" void kernel_launch(void* const* d_in, const int* in_sizes, int n_in,
                              void* d_out, int out_size, void* d_ws, size_t ws_size,
                              hipStream_t stream) {
    (void)in_sizes; (void)n_in; (void)out_size; (void)ws_size;
    const float* x     = (const float*)d_in[0];
    const float* W_ih  = (const float*)d_in[1];
    const float* W_hh  = (const float*)d_in[2];
    const float* b_ih  = (const float*)d_in[3];
    const float* b_hh  = (const float*)d_in[4];
    const float* W_lin = (const float*)d_in[5];
    const float* b_lin = (const float*)d_in[6];
    float* out = (float*)d_out;

    char* ws = (char*)d_ws;
    unsigned* flg = (unsigned*)ws;              // 512*16*16*4 = 524288 B
    u32* hb = (u32*)(ws + 524288);              // 2*16*16*256*4 = 524288 B

    hipMemsetAsync(flg, 0, (size_t)T_STEPS * NBG * 16 * sizeof(unsigned), stream);
    lstm_pipe_kernel<<<dim3(NBG * NCG), dim3(NTHR), 0, stream>>>(
        x, W_ih, W_hh, b_ih, b_hh, W_lin, b_lin, out, hb, flg);
}

// Round 11
// 1266.446 us; speedup vs baseline: 8.4939x; 1.5358x over previous
//
#include <hip/hip_runtime.h>
#include <stdint.h>

#define T_STEPS 512
#define H_DIM   256
#define NBG     16
#define NCG     8
#define BM      16
#define NTHR    512

typedef unsigned short u16;
typedef unsigned int   u32;
typedef __attribute__((ext_vector_type(8))) short short8;
typedef __attribute__((ext_vector_type(4))) float f32x4;
typedef __attribute__((ext_vector_type(4))) u32   u32x4;

// tag written at step t (alternates per slot reuse; 0xAA-poison/zero LSB=0
// never matches the first expected tag=1)
#define TAG(t) ((((unsigned)(t) >> 1) & 1u) ^ 1u)

__device__ __forceinline__ u16 f2bf(float f) {
    unsigned u = __float_as_uint(f);
    unsigned r = (u + 0x7fffu + ((u >> 16) & 1u)) >> 16;
    return (u16)r;
}
__device__ __forceinline__ float bf2f(u16 h) {
    return __uint_as_float(((unsigned)h) << 16);
}
__device__ __forceinline__ float sigmoid_f(float v) {
    return 1.0f / (1.0f + __expf(-v));
}
__device__ __forceinline__ float tanh_f(float v) {
    float e = __expf(2.0f * v);
    return 1.0f - 2.0f / (e + 1.0f);
}

// L3-direct loads/stores (sc0 sc1): coherent at L3, no L2 invalidates, no wbl2.
__device__ __forceinline__ void bypass_load_2x16(const u32* p0, const u32* p1,
                                                 u32x4& d0, u32x4& d1) {
    asm volatile("global_load_dwordx4 %0, %2, off sc0 sc1\n\t"
                 "global_load_dwordx4 %1, %3, off sc0 sc1\n\t"
                 "s_waitcnt vmcnt(0)"
                 : "=&v"(d0), "=&v"(d1)
                 : "v"(p0), "v"(p1) : "memory");
}
__device__ __forceinline__ void bypass_store_u32(u32* p, u32 v) {
    asm volatile("global_store_dword %0, %1, off sc0 sc1"
                 :: "v"(p), "v"(v) : "memory");
}

// Grid: 128 blocks = 16 batch-groups (bg) x 8 col-groups (g). W_hh slice in
// registers (bf16 hi/lo 3-product split). h exchanged as self-validating
// tagged u32 ((hi<<16)|(lo&~1)|tag) via sc0/sc1 write-through. NO flag array,
// NO atomics, NO wbl2: the stage threads poll their own data words until all
// 8 tags match (one L3 trip = discovery + data). 2 barriers/step.
__global__ void __launch_bounds__(NTHR, 1)
lstm_pipe_kernel(const float* __restrict__ x,
                 const float* __restrict__ W_ih,
                 const float* __restrict__ W_hh,
                 const float* __restrict__ b_ih,
                 const float* __restrict__ b_hh,
                 const float* __restrict__ W_lin,
                 const float* __restrict__ b_lin,
                 float* __restrict__ out,
                 u32* __restrict__ hb)
{
    const int tid  = threadIdx.x;
    const int bg   = blockIdx.x & (NBG - 1);
    const int g    = blockIdx.x >> 4;
    const int wave = tid >> 6;
    const int lane = tid & 63;
    const int cl   = lane & 15;   // MFMA A-row / D-col
    const int kgrp = lane >> 4;

    __shared__ __align__(16) u16 HShi[BM * H_DIM];   // staged h_{t-1} hi (swizzled)
    __shared__ __align__(16) u16 HSlo[BM * H_DIM];   // staged h_{t-1} lo (swizzled)
    __shared__ float gtmp2[BM * 132];                // [m][c_block], conflict-free
    __shared__ float wlin[H_DIM];

    // ---- W_hh fragments (persistent in registers), bf16 hi/lo split ----
    // B-frag (16x16x32): lane holds B[k = kt*32 + kgrp*8 + e][col = cl]
    short8 wfh[8], wfl[8];
    {
        const int c    = wave * 16 + cl;                       // 0..127
        const int wrow = (c & 3) * H_DIM + g * 32 + (c >> 2);  // gate*H + hidden
        const float* wr = W_hh + (size_t)wrow * H_DIM;
        #pragma unroll
        for (int kt = 0; kt < 8; ++kt) {
            const int k0 = kt * 32 + kgrp * 8;
            short8 hi8, lo8;
            #pragma unroll
            for (int e = 0; e < 8; ++e) {
                float w = wr[k0 + e];
                u16 hi = f2bf(w);
                u16 lo = f2bf(w - bf2f(hi));
                hi8[e] = (short)hi;
                lo8[e] = (short)lo;
            }
            wfh[kt] = hi8;
            wfl[kt] = lo8;
        }
    }

    // ---- pointwise mapping (coalesced): m2 = tid>>5, j2 = tid&31 ----
    const int m2     = tid >> 5;
    const int j2     = tid & 31;
    const int jglob2 = g * 32 + j2;
    float bias4[4], wihr[4][3];
    #pragma unroll
    for (int gi = 0; gi < 4; ++gi) {
        const int row = gi * H_DIM + jglob2;
        bias4[gi]  = b_ih[row] + b_hh[row];
        wihr[gi][0] = W_ih[row * 3 + 0];
        wihr[gi][1] = W_ih[row * 3 + 1];
        wihr[gi][2] = W_ih[row * 3 + 2];
    }
    if (tid < H_DIM) wlin[tid] = W_lin[tid];
    const float blin = b_lin[0];
    const float* xrow = x + (size_t)(bg * BM + m2) * (T_STEPS * 3);

    // ---- staging mapping: sm = tid>>5 row, skb = tid&31 col-block ----
    const int sm    = tid >> 5;
    const int skb   = tid & 31;
    const int sdidx = (sm * H_DIM + skb * 8) ^ ((sm & 7) << 3);   // u16 units

    // ---- y-projection mapping (all 8 waves of g0, 2 rows per wave) ----
    const int m_y  = wave * 2 + (lane >> 5);
    const int kseg = lane & 31;
    const int yidx = (m_y * H_DIM + kseg * 8) ^ ((m_y & 7) << 3);

    float cstate = 0.0f;

    for (int t = 0; t < T_STEPS; ++t) {
        // x_t (independent of h; issues before the poll)
        const float x0 = xrow[t * 3 + 0];
        const float x1 = xrow[t * 3 + 1];
        const float x2 = xrow[t * 3 + 2];

        if (t > 0) {
            // tagged stage-poll: my 8 packed words, all tags must match
            const int slot = (t - 1) & 1;
            const u32* p = hb + (size_t)(slot * NBG + bg) * (BM * H_DIM)
                         + sm * H_DIM + skb * 8;
            const u32 want = TAG(t - 1);
            u32x4 d0, d1;
            for (;;) {
                bypass_load_2x16(p, p + 4, d0, d1);
                const u32 a = d0[0] & d0[1] & d0[2] & d0[3] & d1[0] & d1[1] & d1[2] & d1[3];
                const u32 o = d0[0] | d0[1] | d0[2] | d0[3] | d1[0] | d1[1] | d1[2] | d1[3];
                const bool ok = want ? ((a & 1u) != 0u) : ((o & 1u) == 0u);
                if (ok) break;
                __builtin_amdgcn_s_sleep(1);
            }
            short8 hi8, lo8;
            #pragma unroll
            for (int e = 0; e < 4; ++e) {
                hi8[e]     = (short)(d0[e] >> 16);
                lo8[e]     = (short)(d0[e] & 0xFFFEu);
                hi8[4 + e] = (short)(d1[e] >> 16);
                lo8[4 + e] = (short)(d1[e] & 0xFFFEu);
            }
            *(short8*)&HShi[sdidx] = hi8;
            *(short8*)&HSlo[sdidx] = lo8;
        }
        __syncthreads();   // B: staging visible to all waves
        f32x4 acc0 = {0.f, 0.f, 0.f, 0.f};
        f32x4 acc1 = {0.f, 0.f, 0.f, 0.f};
        if (t > 0) {
            // gates[16,16-tile] += h_{t-1} @ Wslice^T  (3-product bf16 split)
            #pragma unroll
            for (int kt = 0; kt < 8; ++kt) {
                const int aidx = (cl * H_DIM + kt * 32 + kgrp * 8) ^ ((cl & 7) << 3);
                const short8 ah = *(const short8*)&HShi[aidx];
                const short8 al = *(const short8*)&HSlo[aidx];
                acc0 = __builtin_amdgcn_mfma_f32_16x16x32_bf16(ah, wfh[kt], acc0, 0, 0, 0);
                acc1 = __builtin_amdgcn_mfma_f32_16x16x32_bf16(ah, wfl[kt], acc1, 0, 0, 0);
                acc0 = __builtin_amdgcn_mfma_f32_16x16x32_bf16(al, wfh[kt], acc0, 0, 0, 0);
            }
        }
        // D layout: col=cl, row m=kgrp*4+r -> transposed store gtmp2[m][c_block]
        #pragma unroll
        for (int r = 0; r < 4; ++r)
            gtmp2[(kgrp * 4 + r) * 132 + wave * 16 + cl] = acc0[r] + acc1[r];
        // y_{t-1} on g0, all waves, 2 rows each — HS is stable between B and C
        if (g == 0 && t > 0) {
            const short8 hh = *(const short8*)&HShi[yidx];
            const short8 ll = *(const short8*)&HSlo[yidx];
            const float* wl = &wlin[kseg * 8];
            float part = 0.f;
            #pragma unroll
            for (int e = 0; e < 8; ++e)
                part += (bf2f((u16)hh[e]) + bf2f((u16)ll[e])) * wl[e];
            part += __shfl_xor(part, 1);
            part += __shfl_xor(part, 2);
            part += __shfl_xor(part, 4);
            part += __shfl_xor(part, 8);
            part += __shfl_xor(part, 16);
            if (kseg == 0)
                out[(size_t)(bg * BM + m_y) * T_STEPS + (t - 1)] =
                    fmaxf(part + blin, 0.f);
        }
        __syncthreads();   // C: transpose visible; HS free for next staging
        {
            const f32x4 gq = *(const f32x4*)&gtmp2[m2 * 132 + j2 * 4];
            float gv[4];
            #pragma unroll
            for (int gi = 0; gi < 4; ++gi)
                gv[gi] = gq[gi] + bias4[gi]
                       + wihr[gi][0] * x0 + wihr[gi][1] * x1 + wihr[gi][2] * x2;
            const float ig = sigmoid_f(gv[0]);
            const float fg = sigmoid_f(gv[1]);
            const float gg = tanh_f(gv[2]);
            const float og = sigmoid_f(gv[3]);
            cstate = fg * cstate + ig * gg;
            const float hval = og * tanh_f(cstate);
            // self-validating tagged publish (write-through to L3)
            const u16 hhi = f2bf(hval);
            const u16 hlo = f2bf(hval - bf2f(hhi));
            const u32 pk  = ((u32)hhi << 16) | ((u32)hlo & 0xFFFEu) | TAG(t);
            const int slot_t = t & 1;
            bypass_store_u32(hb + (size_t)(slot_t * NBG + bg) * (BM * H_DIM)
                                + (size_t)m2 * H_DIM + jglob2, pk);
        }
        // no barrier: next iteration's per-thread poll + barrier B cover all
        // cross-thread hazards (LDS writes gated by B, gtmp2 writes by next C)
    }
    // final column y[:, T-1] on g0: stage h_{T-1} then project
    if (g == 0) {
        const int slot = (T_STEPS - 1) & 1;
        const u32* p = hb + (size_t)(slot * NBG + bg) * (BM * H_DIM)
                     + sm * H_DIM + skb * 8;
        const u32 want = TAG(T_STEPS - 1);
        u32x4 d0, d1;
        for (;;) {
            bypass_load_2x16(p, p + 4, d0, d1);
            const u32 a = d0[0] & d0[1] & d0[2] & d0[3] & d1[0] & d1[1] & d1[2] & d1[3];
            const u32 o = d0[0] | d0[1] | d0[2] | d0[3] | d1[0] | d1[1] | d1[2] | d1[3];
            const bool ok = want ? ((a & 1u) != 0u) : ((o & 1u) == 0u);
            if (ok) break;
            __builtin_amdgcn_s_sleep(1);
        }
        short8 hi8, lo8;
        #pragma unroll
        for (int e = 0; e < 4; ++e) {
            hi8[e]     = (short)(d0[e] >> 16);
            lo8[e]     = (short)(d0[e] & 0xFFFEu);
            hi8[4 + e] = (short)(d1[e] >> 16);
            lo8[4 + e] = (short)(d1[e] & 0xFFFEu);
        }
        *(short8*)&HShi[sdidx] = hi8;
        *(short8*)&HSlo[sdidx] = lo8;
        __syncthreads();
        const short8 hh = *(const short8*)&HShi[yidx];
        const short8 ll = *(const short8*)&HSlo[yidx];
        const float* wl = &wlin[kseg * 8];
        float part = 0.f;
        #pragma unroll
        for (int e = 0; e < 8; ++e)
            part += (bf2f((u16)hh[e]) + bf2f((u16)ll[e])) * wl[e];
        part += __shfl_xor(part, 1);
        part += __shfl_xor(part, 2);
        part += __shfl_xor(part, 4);
        part += __shfl_xor(part, 8);
        part += __shfl_xor(part, 16);
        if (kseg == 0)
            out[(size_t)(bg * BM + m_y) * T_STEPS + (T_STEPS - 1)] =
                fmaxf(part + blin, 0.f);
    }
}

extern "C" void kernel_launch(void* const* d_in, const int* in_sizes, int n_in,
                              void* d_out, int out_size, void* d_ws, size_t ws_size,
                              hipStream_t stream) {
    (void)in_sizes; (void)n_in; (void)out_size; (void)ws_size;
    const float* x     = (const float*)d_in[0];
    const float* W_ih  = (const float*)d_in[1];
    const float* W_hh  = (const float*)d_in[2];
    const float* b_ih  = (const float*)d_in[3];
    const float* b_hh  = (const float*)d_in[4];
    const float* W_lin = (const float*)d_in[5];
    const float* b_lin = (const float*)d_in[6];
    float* out = (float*)d_out;

    u32* hb = (u32*)d_ws;   // 2*16*16*256*4 = 524288 B, tagged h exchange

    // zero-fill: LSB=0 never matches the first expected tag (=1)
    hipMemsetAsync(hb, 0, (size_t)2 * NBG * BM * H_DIM * sizeof(u32), stream);
    lstm_pipe_kernel<<<dim3(NBG * NCG), dim3(NTHR), 0, stream>>>(
        x, W_ih, W_hh, b_ih, b_hh, W_lin, b_lin, out, hb);
}